// Round 2
// baseline (892.092 us; speedup 1.0000x reference)
//
#include <hip/hip_runtime.h>
#include <stdint.h>

#define N_PTS 100000
#define M_PTS 131072

typedef unsigned short u16;
typedef __attribute__((ext_vector_type(8))) short bf16x8;
typedef __attribute__((ext_vector_type(4))) float f32x4;

__device__ __forceinline__ u16 f2bf(float x) {
    union { float f; uint32_t u; } v; v.f = x;
    uint32_t r = v.u + 0x7fffu + ((v.u >> 16) & 1u);
    return (u16)(r >> 16);
}
__device__ __forceinline__ float bf2f(u16 b) {
    union { uint32_t u; float f; } v; v.u = ((uint32_t)b) << 16;
    return v.f;
}
__device__ __forceinline__ bf16x8 cvt8(const float* __restrict__ p) {
    float4 x0 = *(const float4*)p;
    float4 x1 = *(const float4*)(p + 4);
    bf16x8 r;
    r[0]=(short)f2bf(x0.x); r[1]=(short)f2bf(x0.y);
    r[2]=(short)f2bf(x0.z); r[3]=(short)f2bf(x0.w);
    r[4]=(short)f2bf(x1.x); r[5]=(short)f2bf(x1.y);
    r[6]=(short)f2bf(x1.z); r[7]=(short)f2bf(x1.w);
    return r;
}

// ---------------- K1: qkv = feat @ Wqkv^T + bqkv  -> bf16 (N x 768) --------
// MFMA layouts (16x16x32 bf16): A[i][k]: i=lane&15, k=(lane>>4)*8+b
//                               B[k][j]: j=lane&15, k=(lane>>4)*8+b
//                               D[i][j]: j=lane&15, i=(lane>>4)*4+r  (m89-verified)
__global__ __launch_bounds__(256) void qkv_gemm(
    const float* __restrict__ feat, const float* __restrict__ Wqkv,
    const float* __restrict__ bqkv, u16* __restrict__ qkvb)
{
    const int jt = blockIdx.x;   // 0..5   (768 / 128)
    const int nt = blockIdx.y;   // 0..781 (ceil(100000/128))
    const int tid = threadIdx.x;
    const int w = tid >> 6, l = tid & 63;
    const int lr = l & 15, lk = l >> 4;
    const int n0 = nt*128 + (w>>1)*64;
    const int j0 = jt*128 + (w&1)*64;

    f32x4 acc[4][4];
    #pragma unroll
    for (int a=0;a<4;a++)
      #pragma unroll
      for (int b=0;b<4;b++) acc[a][b] = (f32x4)0.0f;

    for (int k=0;k<256;k+=32) {
        bf16x8 af[4], bfr[4];
        #pragma unroll
        for (int f=0;f<4;f++) {
            int row = n0 + f*16 + lr;
            if (row < N_PTS) af[f] = cvt8(feat + (size_t)row*256 + k + lk*8);
            else             af[f] = (bf16x8)0;
        }
        #pragma unroll
        for (int f=0;f<4;f++) {
            int col = j0 + f*16 + lr;     // < 768 always
            bfr[f] = cvt8(Wqkv + (size_t)col*256 + k + lk*8);
        }
        #pragma unroll
        for (int a=0;a<4;a++)
          #pragma unroll
          for (int b=0;b<4;b++)
            acc[a][b] = __builtin_amdgcn_mfma_f32_16x16x32_bf16(af[a], bfr[b], acc[a][b], 0,0,0);
    }
    #pragma unroll
    for (int a=0;a<4;a++) {
      #pragma unroll
      for (int b=0;b<4;b++) {
        int col = j0 + b*16 + lr;
        float bias = bqkv[col];
        #pragma unroll
        for (int r=0;r<4;r++) {
            int row = n0 + a*16 + lk*4 + r;
            if (row < N_PTS)
                qkvb[(size_t)row*768 + col] = f2bf(acc[a][b][r] + bias);
        }
      }
    }
}

// ---------------- K2: gather + RoPE + blocked attention --------------------
// One block per (p, head). 4 waves; wave w owns score/output rows 32w..32w+31.
__global__ __launch_bounds__(256) void attn_kernel(
    const u16* __restrict__ qkvb, const int* __restrict__ pinv,
    const float* __restrict__ cosb, const float* __restrict__ sinb,
    u16* __restrict__ attnout)
{
    const int h = blockIdx.x;    // 0..7
    const int p = blockIdx.y;    // 0..1023
    const int tid = threadIdx.x;

    // stride 40 u16 = 80 B: b128 row reads land on 8 distinct bank groups (2-way = free)
    __shared__ u16 qb[128][40];
    __shared__ u16 kb[128][40];
    __shared__ u16 vT[32][136];   // V transposed: [d][token], k-contiguous B-frag reads
    __shared__ u16 Pb[128][136];  // softmax probs bf16 (lane-transpose via LDS)

    {   // gather + RoPE: 2 threads per token (part0: Q, part1: K + V)
        const int i = tid >> 1, part = tid & 1;
        const int m = p*128 + i;
        const int r = pinv[m];
        const u16* base = qkvb + (size_t)r*768 + part*256 + h*32;
        u16 vals[32];
        *(uint4*)(vals+0)  = *(const uint4*)(base+0);
        *(uint4*)(vals+8)  = *(const uint4*)(base+8);
        *(uint4*)(vals+16) = *(const uint4*)(base+16);
        *(uint4*)(vals+24) = *(const uint4*)(base+24);
        const float* cr = cosb + (size_t)m*32;
        const float* sr = sinb + (size_t)m*32;
        u16 o[32];
        #pragma unroll
        for (int d=0; d<16; d++) {
            float x1 = bf2f(vals[d]), x2 = bf2f(vals[d+16]);
            float c = cr[d], s = sr[d];
            o[d]    = f2bf(x1*c - x2*s);
            o[d+16] = f2bf(x2*c + x1*s);
        }
        u16 (*dst)[40] = part ? kb : qb;
        *(uint4*)&dst[i][0]  = *(uint4*)(o+0);
        *(uint4*)&dst[i][8]  = *(uint4*)(o+8);
        *(uint4*)&dst[i][16] = *(uint4*)(o+16);
        *(uint4*)&dst[i][24] = *(uint4*)(o+24);
        if (part) {
            const u16* vbase = qkvb + (size_t)r*768 + 512 + h*32;
            #pragma unroll
            for (int dd=0; dd<32; dd+=8) {
                u16 tv[8];
                *(uint4*)tv = *(const uint4*)(vbase+dd);
                #pragma unroll
                for (int b=0;b<8;b++) vT[dd+b][i] = tv[b];
            }
        }
    }
    __syncthreads();

    const int w = tid>>6, l = tid&63, lr = l&15, lk = l>>4;
    const float scale = 0.17677669529663687f;   // 1/sqrt(32)

    // QK^T: K-dim = D = 32 -> exactly one MFMA per 16x16 score tile
    f32x4 sf[2][8];
    #pragma unroll
    for (int mt=0; mt<2; mt++) {
        const int rb = w*32 + mt*16;
        bf16x8 a = *(const bf16x8*)&qb[rb+lr][lk*8];
        #pragma unroll
        for (int nt=0; nt<8; nt++) {
            bf16x8 b = *(const bf16x8*)&kb[nt*16+lr][lk*8];
            sf[mt][nt] = __builtin_amdgcn_mfma_f32_16x16x32_bf16(a, b, (f32x4)0.0f, 0,0,0);
        }
    }
    // register softmax: row i = lk*4+r lives in the 16 lanes sharing lk; xor masks 1,2,4,8
    #pragma unroll
    for (int mt=0; mt<2; mt++) {
      #pragma unroll
      for (int r=0; r<4; r++) {
        float mx = -1e30f;
        #pragma unroll
        for (int nt=0; nt<8; nt++) {
            sf[mt][nt][r] *= scale;
            mx = fmaxf(mx, sf[mt][nt][r]);
        }
        #pragma unroll
        for (int msk=1; msk<16; msk<<=1) mx = fmaxf(mx, __shfl_xor(mx, msk));
        float sum = 0.f;
        #pragma unroll
        for (int nt=0; nt<8; nt++) {
            float e = __expf(sf[mt][nt][r] - mx);
            sf[mt][nt][r] = e;
            sum += e;
        }
        #pragma unroll
        for (int msk=1; msk<16; msk<<=1) sum += __shfl_xor(sum, msk);
        float inv = 1.f / sum;
        int row = w*32 + mt*16 + lk*4 + r;
        #pragma unroll
        for (int nt=0; nt<8; nt++)
            Pb[row][nt*16+lr] = f2bf(sf[mt][nt][r] * inv);
      }
    }
    // PV: O(32x32 per wave) = P(32x128) @ V(128x32)
    #pragma unroll
    for (int mt=0; mt<2; mt++) {
        const int rb = w*32 + mt*16;
        #pragma unroll
        for (int nt=0; nt<2; nt++) {
            f32x4 acc = (f32x4)0.0f;
            #pragma unroll
            for (int ks=0; ks<4; ks++) {
                bf16x8 a = *(const bf16x8*)&Pb[rb+lr][ks*32 + lk*8];
                bf16x8 b = *(const bf16x8*)&vT[nt*16+lr][ks*32 + lk*8];
                acc = __builtin_amdgcn_mfma_f32_16x16x32_bf16(a, b, acc, 0,0,0);
            }
            #pragma unroll
            for (int r=0;r<4;r++) {
                int token = p*128 + rb + lk*4 + r;
                attnout[(size_t)token*256 + h*32 + nt*16 + lr] = f2bf(acc[r]);
            }
        }
    }
}

// ---------------- K3: proj GEMM + atomic scatter into segment sums ---------
__global__ __launch_bounds__(256) void proj_scatter(
    const u16* __restrict__ attnout, const float* __restrict__ Wproj,
    const float* __restrict__ bproj, const int* __restrict__ pinv,
    float* __restrict__ out)
{
    const int jt = blockIdx.x;   // 0..1
    const int mt = blockIdx.y;   // 0..1023
    const int tid = threadIdx.x;
    const int w = tid >> 6, l = tid & 63;
    const int lr = l & 15, lk = l >> 4;
    const int m0 = mt*128 + (w>>1)*64;
    const int j0 = jt*128 + (w&1)*64;

    f32x4 acc[4][4];
    #pragma unroll
    for (int a=0;a<4;a++)
      #pragma unroll
      for (int b=0;b<4;b++) acc[a][b] = (f32x4)0.0f;

    for (int k=0;k<256;k+=32) {
        bf16x8 af[4], bfr[4];
        #pragma unroll
        for (int f=0;f<4;f++)
            af[f] = *(const bf16x8*)(attnout + (size_t)(m0 + f*16 + lr)*256 + k + lk*8);
        #pragma unroll
        for (int f=0;f<4;f++)
            bfr[f] = cvt8(Wproj + (size_t)(j0 + f*16 + lr)*256 + k + lk*8);
        #pragma unroll
        for (int a=0;a<4;a++)
          #pragma unroll
          for (int b=0;b<4;b++)
            acc[a][b] = __builtin_amdgcn_mfma_f32_16x16x32_bf16(af[a], bfr[b], acc[a][b], 0,0,0);
    }
    #pragma unroll
    for (int a=0;a<4;a++) {
      #pragma unroll
      for (int b=0;b<4;b++) {
        int col = j0 + b*16 + lr;
        float bias = bproj[col];
        #pragma unroll
        for (int r=0;r<4;r++) {
            int token = m0 + a*16 + lk*4 + r;
            int seg = pinv[token];
            atomicAdd(out + (size_t)seg*256 + col, acc[a][b][r] + bias);
        }
      }
    }
}

// ---------------- K4: segment counts ---------------------------------------
__global__ __launch_bounds__(256) void count_kernel(const int* __restrict__ pinv,
                                                    float* __restrict__ cnt)
{
    int m = blockIdx.x*256 + threadIdx.x;
    if (m < M_PTS) atomicAdd(cnt + pinv[m], 1.0f);
}

// ---------------- K5: normalize (mean) in place ----------------------------
__global__ __launch_bounds__(256) void finalize_kernel(float* __restrict__ out,
                                                       const float* __restrict__ cnt)
{
    long long i = (long long)blockIdx.x*256 + threadIdx.x;
    if (i < (long long)N_PTS*256) {
        float c = cnt[i >> 8];
        float v = out[i];
        out[i] = (c > 0.f) ? v / c : 0.f;
    }
}

extern "C" void kernel_launch(void* const* d_in, const int* in_sizes, int n_in,
                              void* d_out, int out_size, void* d_ws, size_t ws_size,
                              hipStream_t stream)
{
    const float* feat  = (const float*)d_in[0];
    // d_in[1] path_coord, d_in[3] path_offset: unused by reference math
    const int*   pinv  = (const int*)d_in[2];
    const float* cosb  = (const float*)d_in[4];
    const float* sinb  = (const float*)d_in[5];
    const float* Wqkv  = (const float*)d_in[6];
    const float* bqkv  = (const float*)d_in[7];
    const float* Wproj = (const float*)d_in[8];
    const float* bproj = (const float*)d_in[9];
    float* out = (float*)d_out;

    char* ws = (char*)d_ws;
    u16* qkvb = (u16*)ws;                                  // 100000*768*2 = 153.6 MB
    size_t off0 = (size_t)N_PTS*768*2;
    u16* attnout = (u16*)(ws + off0);                      // 131072*256*2 = 67.1 MB
    size_t off1 = off0 + (size_t)M_PTS*256*2;
    float* cnt = (float*)(ws + off1);                      // 0.4 MB

    hipMemsetAsync(out, 0, (size_t)out_size*sizeof(float), stream);
    hipMemsetAsync(cnt, 0, (size_t)N_PTS*sizeof(float), stream);

    qkv_gemm     <<<dim3(6, 782),  256, 0, stream>>>(feat, Wqkv, bqkv, qkvb);
    attn_kernel  <<<dim3(8, 1024), 256, 0, stream>>>(qkvb, pinv, cosb, sinb, attnout);
    proj_scatter <<<dim3(2, 1024), 256, 0, stream>>>(attnout, Wproj, bproj, pinv, out);
    count_kernel <<<512, 256, 0, stream>>>(pinv, cnt);
    finalize_kernel<<<100000, 256, 0, stream>>>(out, cnt);
}

// Round 3
// 766.789 us; speedup vs baseline: 1.1634x; 1.1634x over previous
//
#include <hip/hip_runtime.h>
#include <stdint.h>

#define N_PTS 100000
#define M_PTS 131072

typedef unsigned short u16;
typedef __attribute__((ext_vector_type(8))) short bf16x8;
typedef __attribute__((ext_vector_type(4))) float f32x4;

__device__ __forceinline__ u16 f2bf(float x) {
    union { float f; uint32_t u; } v; v.f = x;
    uint32_t r = v.u + 0x7fffu + ((v.u >> 16) & 1u);
    return (u16)(r >> 16);
}
__device__ __forceinline__ float bf2f(u16 b) {
    union { uint32_t u; float f; } v; v.u = ((uint32_t)b) << 16;
    return v.f;
}
__device__ __forceinline__ bf16x8 cvt8(const float* __restrict__ p) {
    float4 x0 = *(const float4*)p;
    float4 x1 = *(const float4*)(p + 4);
    bf16x8 r;
    r[0]=(short)f2bf(x0.x); r[1]=(short)f2bf(x0.y);
    r[2]=(short)f2bf(x0.z); r[3]=(short)f2bf(x0.w);
    r[4]=(short)f2bf(x1.x); r[5]=(short)f2bf(x1.y);
    r[6]=(short)f2bf(x1.z); r[7]=(short)f2bf(x1.w);
    return r;
}

// ---------------- K0: preconvert weights to bf16 (L2-resident B) -----------
__global__ __launch_bounds__(256) void conv_weights(
    const float* __restrict__ Wqkv, const float* __restrict__ Wproj,
    u16* __restrict__ Wqkvb, u16* __restrict__ Wprojb)
{
    int i = blockIdx.x*256 + threadIdx.x;   // grid 768 -> 196608 threads
    Wqkvb[i] = f2bf(Wqkv[i]);
    if (i < 65536) Wprojb[i] = f2bf(Wproj[i]);
}

// ---------------- K1: qkv = feat @ Wqkv^T + bqkv  -> bf16 (N x 768) --------
// One block per 128-row tile; A staged in LDS bf16 ONCE, reused across the
// 6 column tiles (jt). B (Wqkv bf16, 393 KB) stays L2-resident.
// LDS layout: at[row][chunk^(row&7)] (8-elem chunks) -> 2-way b128, 64 KB.
__global__ __launch_bounds__(256) void qkv_gemm(
    const float* __restrict__ feat, const u16* __restrict__ Wqkvb,
    const float* __restrict__ bqkv, u16* __restrict__ qkvb)
{
    const int nt = blockIdx.x;   // 0..781
    const int tid = threadIdx.x;
    __shared__ u16 at[128][256];

    {   // stage A-tile: thread t -> row t>>1, col-half (t&1)*128
        const int row = tid >> 1, ch0 = (tid & 1) * 16;   // chunk base (8 u16/chunk)
        const int grow = nt*128 + row;
        const int swb = row & 7;
        if (grow < N_PTS) {
            const float* src = feat + (size_t)grow*256 + ch0*8;
            #pragma unroll
            for (int i=0;i<16;i++) {
                bf16x8 v = cvt8(src + i*8);
                *(bf16x8*)&at[row][((ch0+i)^swb)*8] = v;
            }
        } else {
            #pragma unroll
            for (int i=0;i<16;i++)
                *(bf16x8*)&at[row][((ch0+i)^swb)*8] = (bf16x8)0;
        }
    }
    __syncthreads();

    const int w = tid>>6, l = tid&63, lr = l&15, lk = l>>4;
    const int r0 = (w>>1)*64;
    const int n0 = nt*128 + r0;
    const int swr = lr & 7;       // row&7 for A-frag reads (r0,f*16 are mult of 8)

    for (int jt=0; jt<6; jt++) {
        const int j0 = jt*128 + (w&1)*64;
        f32x4 acc[4][4];
        #pragma unroll
        for (int a=0;a<4;a++)
          #pragma unroll
          for (int b=0;b<4;b++) acc[a][b] = (f32x4)0.0f;

        for (int k=0;k<256;k+=32) {
            const int cc = (k>>3) + lk;
            bf16x8 af[4], bfr[4];
            #pragma unroll
            for (int f=0;f<4;f++)
                af[f] = *(const bf16x8*)&at[r0 + f*16 + lr][(cc^swr)*8];
            #pragma unroll
            for (int f=0;f<4;f++)
                bfr[f] = *(const bf16x8*)(Wqkvb + (size_t)(j0 + f*16 + lr)*256 + k + lk*8);
            #pragma unroll
            for (int a=0;a<4;a++)
              #pragma unroll
              for (int b=0;b<4;b++)
                acc[a][b] = __builtin_amdgcn_mfma_f32_16x16x32_bf16(af[a], bfr[b], acc[a][b], 0,0,0);
        }
        #pragma unroll
        for (int a=0;a<4;a++) {
          #pragma unroll
          for (int b=0;b<4;b++) {
            int col = j0 + b*16 + lr;
            float bias = bqkv[col];
            #pragma unroll
            for (int r=0;r<4;r++) {
                int row = n0 + a*16 + lk*4 + r;
                if (row < N_PTS)
                    qkvb[(size_t)row*768 + col] = f2bf(acc[a][b][r] + bias);
            }
          }
        }
    }
}

// ---------------- K2: gather + RoPE + blocked attention --------------------
// One block per (p, head). 4 waves; wave w owns score/output rows 32w..32w+31.
__global__ __launch_bounds__(256) void attn_kernel(
    const u16* __restrict__ qkvb, const int* __restrict__ pinv,
    const float* __restrict__ cosb, const float* __restrict__ sinb,
    u16* __restrict__ attnout)
{
    const int h = blockIdx.x;    // 0..7
    const int p = blockIdx.y;    // 0..1023
    const int tid = threadIdx.x;

    __shared__ u16 qb[128][40];
    __shared__ u16 kb[128][40];
    __shared__ u16 vT[32][136];   // V transposed: [d][token]
    __shared__ u16 Pb[128][136];  // softmax probs bf16

    {   // gather + RoPE: 2 threads per token (part0: Q, part1: K + V)
        const int i = tid >> 1, part = tid & 1;
        const int m = p*128 + i;
        const int r = pinv[m];
        const u16* base = qkvb + (size_t)r*768 + part*256 + h*32;
        u16 vals[32];
        *(uint4*)(vals+0)  = *(const uint4*)(base+0);
        *(uint4*)(vals+8)  = *(const uint4*)(base+8);
        *(uint4*)(vals+16) = *(const uint4*)(base+16);
        *(uint4*)(vals+24) = *(const uint4*)(base+24);
        const float* cr = cosb + (size_t)m*32;
        const float* sr = sinb + (size_t)m*32;
        u16 o[32];
        #pragma unroll
        for (int d=0; d<16; d++) {
            float x1 = bf2f(vals[d]), x2 = bf2f(vals[d+16]);
            float c = cr[d], s = sr[d];
            o[d]    = f2bf(x1*c - x2*s);
            o[d+16] = f2bf(x2*c + x1*s);
        }
        u16 (*dst)[40] = part ? kb : qb;
        *(uint4*)&dst[i][0]  = *(uint4*)(o+0);
        *(uint4*)&dst[i][8]  = *(uint4*)(o+8);
        *(uint4*)&dst[i][16] = *(uint4*)(o+16);
        *(uint4*)&dst[i][24] = *(uint4*)(o+24);
        if (part) {
            const u16* vbase = qkvb + (size_t)r*768 + 512 + h*32;
            #pragma unroll
            for (int dd=0; dd<32; dd+=8) {
                u16 tv[8];
                *(uint4*)tv = *(const uint4*)(vbase+dd);
                #pragma unroll
                for (int b=0;b<8;b++) vT[dd+b][i] = tv[b];
            }
        }
    }
    __syncthreads();

    const int w = tid>>6, l = tid&63, lr = l&15, lk = l>>4;
    const float scale = 0.17677669529663687f;   // 1/sqrt(32)

    f32x4 sf[2][8];
    #pragma unroll
    for (int mt=0; mt<2; mt++) {
        const int rb = w*32 + mt*16;
        bf16x8 a = *(const bf16x8*)&qb[rb+lr][lk*8];
        #pragma unroll
        for (int nt=0; nt<8; nt++) {
            bf16x8 b = *(const bf16x8*)&kb[nt*16+lr][lk*8];
            sf[mt][nt] = __builtin_amdgcn_mfma_f32_16x16x32_bf16(a, b, (f32x4)0.0f, 0,0,0);
        }
    }
    #pragma unroll
    for (int mt=0; mt<2; mt++) {
      #pragma unroll
      for (int r=0; r<4; r++) {
        float mx = -1e30f;
        #pragma unroll
        for (int nt=0; nt<8; nt++) {
            sf[mt][nt][r] *= scale;
            mx = fmaxf(mx, sf[mt][nt][r]);
        }
        #pragma unroll
        for (int msk=1; msk<16; msk<<=1) mx = fmaxf(mx, __shfl_xor(mx, msk));
        float sum = 0.f;
        #pragma unroll
        for (int nt=0; nt<8; nt++) {
            float e = __expf(sf[mt][nt][r] - mx);
            sf[mt][nt][r] = e;
            sum += e;
        }
        #pragma unroll
        for (int msk=1; msk<16; msk<<=1) sum += __shfl_xor(sum, msk);
        float inv = 1.f / sum;
        int row = w*32 + mt*16 + lk*4 + r;
        #pragma unroll
        for (int nt=0; nt<8; nt++)
            Pb[row][nt*16+lr] = f2bf(sf[mt][nt][r] * inv);
      }
    }
    #pragma unroll
    for (int mt=0; mt<2; mt++) {
        const int rb = w*32 + mt*16;
        #pragma unroll
        for (int nt=0; nt<2; nt++) {
            f32x4 acc = (f32x4)0.0f;
            #pragma unroll
            for (int ks=0; ks<4; ks++) {
                bf16x8 a = *(const bf16x8*)&Pb[rb+lr][ks*32 + lk*8];
                bf16x8 b = *(const bf16x8*)&vT[nt*16+lr][ks*32 + lk*8];
                acc = __builtin_amdgcn_mfma_f32_16x16x32_bf16(a, b, acc, 0,0,0);
            }
            #pragma unroll
            for (int r=0;r<4;r++) {
                int token = p*128 + rb + lk*4 + r;
                attnout[(size_t)token*256 + h*32 + nt*16 + lr] = f2bf(acc[r]);
            }
        }
    }
}

// ---------------- K3: proj GEMM + atomic scatter into segment sums ---------
__global__ __launch_bounds__(256) void proj_scatter(
    const u16* __restrict__ attnout, const u16* __restrict__ Wprojb,
    const float* __restrict__ bproj, const int* __restrict__ pinv,
    float* __restrict__ out)
{
    const int jt = blockIdx.x;   // 0..1
    const int mt = blockIdx.y;   // 0..1023
    const int tid = threadIdx.x;
    const int w = tid >> 6, l = tid & 63;
    const int lr = l & 15, lk = l >> 4;
    const int m0 = mt*128 + (w>>1)*64;
    const int j0 = jt*128 + (w&1)*64;

    f32x4 acc[4][4];
    #pragma unroll
    for (int a=0;a<4;a++)
      #pragma unroll
      for (int b=0;b<4;b++) acc[a][b] = (f32x4)0.0f;

    for (int k=0;k<256;k+=32) {
        bf16x8 af[4], bfr[4];
        #pragma unroll
        for (int f=0;f<4;f++)
            af[f] = *(const bf16x8*)(attnout + (size_t)(m0 + f*16 + lr)*256 + k + lk*8);
        #pragma unroll
        for (int f=0;f<4;f++)
            bfr[f] = *(const bf16x8*)(Wprojb + (size_t)(j0 + f*16 + lr)*256 + k + lk*8);
        #pragma unroll
        for (int a=0;a<4;a++)
          #pragma unroll
          for (int b=0;b<4;b++)
            acc[a][b] = __builtin_amdgcn_mfma_f32_16x16x32_bf16(af[a], bfr[b], acc[a][b], 0,0,0);
    }
    #pragma unroll
    for (int a=0;a<4;a++) {
      #pragma unroll
      for (int b=0;b<4;b++) {
        int col = j0 + b*16 + lr;
        float bias = bproj[col];
        #pragma unroll
        for (int r=0;r<4;r++) {
            int token = m0 + a*16 + lk*4 + r;
            int seg = pinv[token];
            atomicAdd(out + (size_t)seg*256 + col, acc[a][b][r] + bias);
        }
      }
    }
}

// ---------------- K4: segment counts ---------------------------------------
__global__ __launch_bounds__(256) void count_kernel(const int* __restrict__ pinv,
                                                    float* __restrict__ cnt)
{
    int m = blockIdx.x*256 + threadIdx.x;
    if (m < M_PTS) atomicAdd(cnt + pinv[m], 1.0f);
}

// ---------------- K5: normalize (mean) in place ----------------------------
__global__ __launch_bounds__(256) void finalize_kernel(float* __restrict__ out,
                                                       const float* __restrict__ cnt)
{
    long long i = (long long)blockIdx.x*256 + threadIdx.x;
    if (i < (long long)N_PTS*256) {
        float c = cnt[i >> 8];
        float v = out[i];
        out[i] = (c > 0.f) ? v / c : 0.f;
    }
}

extern "C" void kernel_launch(void* const* d_in, const int* in_sizes, int n_in,
                              void* d_out, int out_size, void* d_ws, size_t ws_size,
                              hipStream_t stream)
{
    const float* feat  = (const float*)d_in[0];
    const int*   pinv  = (const int*)d_in[2];
    const float* cosb  = (const float*)d_in[4];
    const float* sinb  = (const float*)d_in[5];
    const float* Wqkv  = (const float*)d_in[6];
    const float* bqkv  = (const float*)d_in[7];
    const float* Wproj = (const float*)d_in[8];
    const float* bproj = (const float*)d_in[9];
    float* out = (float*)d_out;

    char* ws = (char*)d_ws;
    u16* qkvb = (u16*)ws;                                  // 153.6 MB
    size_t off0 = (size_t)N_PTS*768*2;
    u16* attnout = (u16*)(ws + off0);                      // 67.1 MB
    size_t off1 = off0 + (size_t)M_PTS*256*2;
    float* cnt = (float*)(ws + off1);                      // 0.4 MB
    size_t off2 = off1 + (size_t)N_PTS*4;
    u16* Wqkvb = (u16*)(ws + off2);                        // 0.39 MB
    size_t off3 = off2 + (size_t)768*256*2;
    u16* Wprojb = (u16*)(ws + off3);                       // 0.13 MB

    hipMemsetAsync(out, 0, (size_t)out_size*sizeof(float), stream);
    hipMemsetAsync(cnt, 0, (size_t)N_PTS*sizeof(float), stream);

    conv_weights <<<768, 256, 0, stream>>>(Wqkv, Wproj, Wqkvb, Wprojb);
    qkv_gemm     <<<782, 256, 0, stream>>>(feat, Wqkvb, bqkv, qkvb);
    attn_kernel  <<<dim3(8, 1024), 256, 0, stream>>>(qkvb, pinv, cosb, sinb, attnout);
    proj_scatter <<<dim3(2, 1024), 256, 0, stream>>>(attnout, Wprojb, bproj, pinv, out);
    count_kernel <<<512, 256, 0, stream>>>(pinv, cnt);
    finalize_kernel<<<100000, 256, 0, stream>>>(out, cnt);
}